// Round 1
// 598.328 us; speedup vs baseline: 1.0188x; 1.0188x over previous
//
#include <hip/hip_runtime.h>

#define BB 4096
#define TT 200
#define DD 128
#define KSHORT 5
// Register-cached trips per 32-lane stream. 13 trips cover rows i < 104, i.e.
// blocks with n <= 104 (majority) never touch memory in pass 2; larger n only
// re-reads the small tail (rows 104..n-1) which is L2/L3-warm.
#define RTRIPS 13

// ---------------------------------------------------------------------------
// A[d][j] = scale * sum_e Wk[e][d] * Wq[e][j]  (so qk = A*mean is pre-scaled).
// Block 0 additionally detects whether hist_mask arrived as int32 (flag=0) or
// 1-byte bool (flag=1): bool bytes packed in a uint give values > 1.
__global__ void precompute_A_kernel(const float* __restrict__ Wq,
                                    const float* __restrict__ Wk,
                                    float* __restrict__ A,
                                    const unsigned* __restrict__ m,
                                    int* __restrict__ flag) {
  __shared__ int s_bad;
  const int d = blockIdx.x, dp = threadIdx.x;
  float acc = 0.f;
#pragma unroll 8
  for (int e = 0; e < DD; ++e) acc += Wk[e * DD + d] * Wq[e * DD + dp];
  A[d * DD + dp] = acc * 0.08838834764831845f;  // 1/sqrt(128)
  if (blockIdx.x == 0) {
    if (dp == 0) s_bad = 0;
    __syncthreads();
    unsigned bad = 0;
#pragma unroll
    for (int i = dp; i < 1024; i += DD) bad |= (m[i] > 1u) ? 1u : 0u;
    if (bad) atomicOr(&s_bad, 1);
    __syncthreads();
    if (dp == 0) *flag = s_bad;
  }
}

// ---------------------------------------------------------------------------
// Fused per-batch kernel. Pass 1 streams the compacted row list from HBM and
// register-caches each lane's float4s; pass 2 replays from registers (no L3
// re-read) except for the rare tail rows i >= 104. Max-free softmax:
// exp(score) = exp(qk.item) * (decay+1e-12), all values in [1e-13, 2].
__global__ __launch_bounds__(256, 4) void fused_kernel(
    const float* __restrict__ items, const void* __restrict__ maskp,
    const float* __restrict__ age, const float* __restrict__ pop,
    const float* __restrict__ Wv, const float* __restrict__ gate_w,
    const float* __restrict__ gate_b, const float* __restrict__ gamma,
    const float* __restrict__ beta, const float* __restrict__ alpha_in,
    const float* __restrict__ A, const int* __restrict__ flagp,
    float* __restrict__ out) {
  __shared__ int   s_idx[TT];                 // compacted row indices
  __shared__ float s_wm[TT], s_ww[TT], s_df[TT];  // compacted: mask, window, exp(bias)
  __shared__ float s_pa[8 * DD];              // per-stream partials (mean / o)
  __shared__ float s_pb[8 * DD];              // per-stream partials (short)
  __shared__ float s_mean[DD], s_qk[DD], s_w[DD], s_user[DD];
  __shared__ float s_l[8];
  __shared__ float s_scal[4];
  __shared__ int   s_n;

  const int b = blockIdx.x, tid = threadIdx.x;
  const int lane32 = tid & 31, stream = tid >> 5;  // 8 row-streams x 32 lanes
  const int mode = *flagp;

  // ---- phase A: mask/age by t-index; count masked rows ----
  float mymask = 0.f, myage = 0.f;
  if (tid == 0) s_n = 0;
  if (tid < TT) {
    int mk = mode ? (int)((const unsigned char*)maskp)[(size_t)b * TT + tid]
                  : ((const int*)maskp)[(size_t)b * TT + tid];
    mymask = mk ? 1.f : 0.f;
    myage = age[(size_t)b * TT + tid];
    s_wm[tid] = mymask;  // t-indexed, only for the count below
  }
  __syncthreads();

  if (tid < 64) {
    float c = 0.f;
    for (int t = tid; t < TT; t += 64) c += s_wm[t];
#pragma unroll
    for (int o = 32; o > 0; o >>= 1) c += __shfl_xor(c, o);
    if (tid == 0) s_scal[0] = c;
  }
  __syncthreads();

  const float cntf = s_scal[0];
  const int cnt = max((int)(cntf + 0.5f), 1);
  const int lo = max(cnt - KSHORT, 0);
  const float dn = (float)(cnt - lo);

  // ---- phase B: compact (unordered) list of needed rows + per-row factors ----
  if (tid < TT) {
    const bool inw = (tid >= lo) && (tid < cnt);
    if (mymask > 0.f || inw) {
      const float al = log1pf(expf(alpha_in[0])) + 1e-6f;  // softplus
      const int p = atomicAdd(&s_n, 1);
      s_idx[p] = tid;
      s_wm[p] = mymask;
      s_ww[p] = inw ? 1.f : 0.f;
      s_df[p] = (mymask > 0.f) ? (__expf(-al * myage) + 1e-12f) : 0.f;
    }
  }
  __syncthreads();
  const int n = s_n;

  // ---- pass 1: branch-free stream -> mean + short partials, register cache ----
  const float* rowbase = items + (size_t)b * (TT * DD) + lane32 * 4;
  float4 r[RTRIPS];
  float4 ms = {0.f, 0.f, 0.f, 0.f}, ss = {0.f, 0.f, 0.f, 0.f};
#pragma unroll
  for (int j = 0; j < RTRIPS; ++j) {
    const int i = stream + j * 8;
    float4 v = {0.f, 0.f, 0.f, 0.f};
    float wm = 0.f, ww = 0.f;
    if (i < n) {
      const int t = s_idx[i];
      wm = s_wm[i];
      ww = s_ww[i];
      v = *(const float4*)(rowbase + t * DD);
    }
    r[j] = v;
    ms.x += wm * v.x; ms.y += wm * v.y; ms.z += wm * v.z; ms.w += wm * v.w;
    ss.x += ww * v.x; ss.y += ww * v.y; ss.z += ww * v.z; ss.w += ww * v.w;
  }
  for (int i = stream + RTRIPS * 8; i < n; i += 8) {  // rare tail (n > 104)
    const int t = s_idx[i];
    const float wm = s_wm[i], ww = s_ww[i];
    const float4 v = *(const float4*)(rowbase + t * DD);
    ms.x += wm * v.x; ms.y += wm * v.y; ms.z += wm * v.z; ms.w += wm * v.w;
    ss.x += ww * v.x; ss.y += ww * v.y; ss.z += ww * v.z; ss.w += ww * v.w;
  }
  *(float4*)&s_pa[stream * DD + lane32 * 4] = ms;
  *(float4*)&s_pb[stream * DD + lane32 * 4] = ss;
  __syncthreads();

  float short_v = 0.f;
  if (tid < DD) {
    float am = 0.f, as = 0.f;
#pragma unroll
    for (int s = 0; s < 8; ++s) { am += s_pa[s * DD + tid]; as += s_pb[s * DD + tid]; }
    s_mean[tid] = am / (cntf + 1e-6f);
    short_v = as / dn;  // kept in register until the blend
  } else if (tid == DD) {
    float sp = 0.f, sr = 0.f;
    for (int t = lo; t < cnt; ++t) {
      sp += pop[(size_t)b * TT + t];
      sr += age[(size_t)b * TT + t];
    }
    const float z = gate_w[0] * (sp / dn) + gate_w[1] * (sr / dn) + gate_b[0];
    s_scal[1] = 1.f / (1.f + expf(-z));
  }
  __syncthreads();

  // ---- qk = A_scaled * mean (A is L2-resident across blocks) ----
  if (tid < DD) {
    const float4* Ar = (const float4*)(A + tid * DD);
    float acc = 0.f;
#pragma unroll
    for (int j = 0; j < DD / 4; ++j) {
      const float4 a4 = Ar[j];
      acc += a4.x * s_mean[4 * j] + a4.y * s_mean[4 * j + 1] +
             a4.z * s_mean[4 * j + 2] + a4.w * s_mean[4 * j + 3];
    }
    s_qk[tid] = acc;
  }
  __syncthreads();

  // ---- pass 2: replay from registers -> max-free softmax-weighted sum ----
  const float4 qk = *(const float4*)&s_qk[lane32 * 4];
  float l = 0.f;
  float4 o = {0.f, 0.f, 0.f, 0.f};
#pragma unroll
  for (int j = 0; j < RTRIPS; ++j) {
    const int i = stream + j * 8;
    if (i < n) {
      const float df = s_df[i];
      const float4 v = r[j];
      float p = qk.x * v.x + qk.y * v.y + qk.z * v.z + qk.w * v.w;
      p += __shfl_xor(p, 1);
      p += __shfl_xor(p, 2);
      p += __shfl_xor(p, 4);
      p += __shfl_xor(p, 8);
      p += __shfl_xor(p, 16);
      const float e = __expf(p) * df;  // df=0 kills window-only rows
      l += e;
      o.x += e * v.x; o.y += e * v.y; o.z += e * v.z; o.w += e * v.w;
    }
  }
  for (int i = stream + RTRIPS * 8; i < n; i += 8) {  // rare tail, L2/L3-warm
    const int t = s_idx[i];
    const float df = s_df[i];
    const float4 v = *(const float4*)(rowbase + t * DD);
    float p = qk.x * v.x + qk.y * v.y + qk.z * v.z + qk.w * v.w;
    p += __shfl_xor(p, 1);
    p += __shfl_xor(p, 2);
    p += __shfl_xor(p, 4);
    p += __shfl_xor(p, 8);
    p += __shfl_xor(p, 16);
    const float e = __expf(p) * df;
    l += e;
    o.x += e * v.x; o.y += e * v.y; o.z += e * v.z; o.w += e * v.w;
  }
  *(float4*)&s_pa[stream * DD + lane32 * 4] = o;
  if (lane32 == 0) s_l[stream] = l;
  __syncthreads();

  // ---- merge streams (plain sums — no max bookkeeping) ----
  if (tid < DD) {
    float O = 0.f;
#pragma unroll
    for (int s = 0; s < 8; ++s) O += s_pa[s * DD + tid];
    float L = 0.f;
#pragma unroll
    for (int s = 0; s < 8; ++s) L += s_l[s];
    s_w[tid] = O / L;
  }
  __syncthreads();

  // ---- long_term = Wv * weighted; gate blend ----
  if (tid < DD) {
    const float4* Wr = (const float4*)(Wv + tid * DD);
    float acc = 0.f;
#pragma unroll
    for (int j = 0; j < DD / 4; ++j) {
      const float4 a4 = Wr[j];
      acc += a4.x * s_w[4 * j] + a4.y * s_w[4 * j + 1] +
             a4.z * s_w[4 * j + 2] + a4.w * s_w[4 * j + 3];
    }
    const float g = s_scal[1];
    s_user[tid] = g * short_v + (1.f - g) * acc;
  }
  __syncthreads();

  // ---- LayerNorm ----
  if (tid < 64) {
    const float x0 = s_user[tid], x1 = s_user[64 + tid];
    float su = x0 + x1;
#pragma unroll
    for (int off = 32; off > 0; off >>= 1) su += __shfl_xor(su, off);
    const float mu = su * (1.f / 128.f);
    const float d0 = x0 - mu, d1 = x1 - mu;
    float s2 = d0 * d0 + d1 * d1;
#pragma unroll
    for (int off = 32; off > 0; off >>= 1) s2 += __shfl_xor(s2, off);
    if (tid == 0) {
      s_scal[2] = mu;
      s_scal[3] = 1.f / sqrtf(s2 * (1.f / 128.f) + 1e-5f);
    }
  }
  __syncthreads();

  if (tid < DD) {
    out[(size_t)b * DD + tid] =
        (s_user[tid] - s_scal[2]) * s_scal[3] * gamma[tid] + beta[tid];
  }
}

// ---------------------------------------------------------------------------
extern "C" void kernel_launch(void* const* d_in, const int* in_sizes, int n_in,
                              void* d_out, int out_size, void* d_ws, size_t ws_size,
                              hipStream_t stream) {
  const float* items  = (const float*)d_in[0];
  const void*  maskp  = d_in[1];
  const float* age    = (const float*)d_in[2];
  const float* pop    = (const float*)d_in[3];
  const float* Wq     = (const float*)d_in[4];
  const float* Wk     = (const float*)d_in[5];
  const float* Wv     = (const float*)d_in[6];
  const float* gate_w = (const float*)d_in[7];
  const float* gate_b = (const float*)d_in[8];
  const float* gamma  = (const float*)d_in[9];
  const float* beta   = (const float*)d_in[10];
  const float* alpha  = (const float*)d_in[11];

  char* ws = (char*)d_ws;
  int*   flag = (int*)ws;            // 256 B
  float* A    = (float*)(ws + 256);  // 64 KB
  float* outp = (float*)d_out;

  precompute_A_kernel<<<DD, DD, 0, stream>>>(Wq, Wk, A, (const unsigned*)maskp, flag);
  fused_kernel<<<BB, 256, 0, stream>>>(items, maskp, age, pop, Wv, gate_w,
                                       gate_b, gamma, beta, alpha, A, flag,
                                       outp);
}

// Round 2
// 589.071 us; speedup vs baseline: 1.0348x; 1.0157x over previous
//
#include <hip/hip_runtime.h>

#define BB 4096
#define TT 200
#define DD 128
#define KSHORT 5
// Register-cached trips per 32-lane stream. 13 trips cover rows i < 104, i.e.
// blocks with n <= 104 (majority) never touch memory in pass 2; larger n only
// re-reads the small tail (rows 104..n-1) which is L2/L3-warm.
#define RTRIPS 13

// ---------------------------------------------------------------------------
// A[d][j] = scale * sum_e Wk[e][d] * Wq[e][j]  (so qk = A*mean is pre-scaled).
// Block 0 additionally detects whether hist_mask arrived as int32 (flag=0) or
// 1-byte bool (flag=1): bool bytes packed in a uint give values > 1.
__global__ void precompute_A_kernel(const float* __restrict__ Wq,
                                    const float* __restrict__ Wk,
                                    float* __restrict__ A,
                                    const unsigned* __restrict__ m,
                                    int* __restrict__ flag) {
  __shared__ int s_bad;
  const int d = blockIdx.x, dp = threadIdx.x;
  float acc = 0.f;
#pragma unroll 8
  for (int e = 0; e < DD; ++e) acc += Wk[e * DD + d] * Wq[e * DD + dp];
  A[d * DD + dp] = acc * 0.08838834764831845f;  // 1/sqrt(128)
  if (blockIdx.x == 0) {
    if (dp == 0) s_bad = 0;
    __syncthreads();
    unsigned bad = 0;
#pragma unroll
    for (int i = dp; i < 1024; i += DD) bad |= (m[i] > 1u) ? 1u : 0u;
    if (bad) atomicOr(&s_bad, 1);
    __syncthreads();
    if (dp == 0) *flag = s_bad;
  }
}

// ---------------------------------------------------------------------------
// Fused per-batch kernel. Ballot-scan compaction produces an ASCENDING row
// list (DRAM-friendly gather order). Pass 1 streams the compacted rows from
// HBM and register-caches each lane's float4s; pass 2 replays from registers
// (no L3 re-read) except for the rare tail rows i >= 104. Max-free softmax:
// exp(score) = exp(qk.item) * (decay+1e-12), all values in [1e-13, 2].
__global__ __launch_bounds__(256, 4) void fused_kernel(
    const float* __restrict__ items, const void* __restrict__ maskp,
    const float* __restrict__ age, const float* __restrict__ pop,
    const float* __restrict__ Wv, const float* __restrict__ gate_w,
    const float* __restrict__ gate_b, const float* __restrict__ gamma,
    const float* __restrict__ beta, const float* __restrict__ alpha_in,
    const float* __restrict__ A, const int* __restrict__ flagp,
    float* __restrict__ out) {
  __shared__ int   s_idx[TT];                 // compacted row indices (ascending)
  __shared__ float s_wm[TT], s_ww[TT], s_df[TT];  // compacted: mask, window, exp(bias)
  __shared__ float s_pa[8 * DD];              // per-stream partials (mean / o)
  __shared__ float s_pb[8 * DD];              // per-stream partials (short)
  __shared__ float s_mean[DD], s_qk[DD], s_w[DD], s_user[DD];
  __shared__ float s_l[8];
  __shared__ float s_scal[6];                 // [0]=cnt [1]=gate [2]=softplus(alpha) [4]=mu [5]=rstd
  __shared__ int   s_wt[4];                   // per-wave compaction counts

  const int b = blockIdx.x, tid = threadIdx.x;
  const int lane32 = tid & 31, stream = tid >> 5;  // 8 row-streams x 32 lanes
  const int mode = *flagp;

  // ---- phase A: mask/age by t-index; softplus(alpha) once ----
  float mymask = 0.f, myage = 0.f;
  if (tid < TT) {
    int mk = mode ? (int)((const unsigned char*)maskp)[(size_t)b * TT + tid]
                  : ((const int*)maskp)[(size_t)b * TT + tid];
    mymask = mk ? 1.f : 0.f;
    myage = age[(size_t)b * TT + tid];
    s_wm[tid] = mymask;  // t-indexed, only for the count below
  } else if (tid == TT) {
    s_scal[2] = log1pf(expf(alpha_in[0])) + 1e-6f;  // softplus
  }
  __syncthreads();

  if (tid < 64) {
    float c = 0.f;
    for (int t = tid; t < TT; t += 64) c += s_wm[t];
#pragma unroll
    for (int o = 32; o > 0; o >>= 1) c += __shfl_xor(c, o);
    if (tid == 0) s_scal[0] = c;
  }
  __syncthreads();

  const float cntf = s_scal[0];
  const int cnt = max((int)(cntf + 0.5f), 1);
  const int lo = max(cnt - KSHORT, 0);
  const float dn = (float)(cnt - lo);

  // ---- phase B: ORDERED compaction via ballot prefix-scan ----
  const bool inw = (tid < TT) && (tid >= lo) && (tid < cnt);
  const bool need = (tid < TT) && (mymask > 0.f || inw);
  const unsigned long long bal = __ballot(need);
  const int lane64 = tid & 63, wv = tid >> 6;
  const int within = __popcll(bal & ((1ULL << lane64) - 1ULL));
  if (lane64 == 0) s_wt[wv] = __popcll(bal);
  __syncthreads();

  int off = 0;
#pragma unroll
  for (int w2 = 0; w2 < 3; ++w2) off += (w2 < wv) ? s_wt[w2] : 0;
  const int n = s_wt[0] + s_wt[1] + s_wt[2] + s_wt[3];
  if (need) {
    const int p = off + within;
    const float al = s_scal[2];
    s_idx[p] = tid;
    s_wm[p] = mymask;
    s_ww[p] = inw ? 1.f : 0.f;
    s_df[p] = (mymask > 0.f) ? (__expf(-al * myage) + 1e-12f) : 0.f;
  }
  __syncthreads();

  // ---- pass 1: branch-free stream -> mean + short partials, register cache ----
  const float* rowbase = items + (size_t)b * (TT * DD) + lane32 * 4;
  float4 r[RTRIPS];
  float4 ms = {0.f, 0.f, 0.f, 0.f}, ss = {0.f, 0.f, 0.f, 0.f};
#pragma unroll
  for (int j = 0; j < RTRIPS; ++j) {
    const int i = stream + j * 8;
    float4 v = {0.f, 0.f, 0.f, 0.f};
    float wm = 0.f, ww = 0.f;
    if (i < n) {
      const int t = s_idx[i];
      wm = s_wm[i];
      ww = s_ww[i];
      v = *(const float4*)(rowbase + t * DD);
    }
    r[j] = v;
    ms.x += wm * v.x; ms.y += wm * v.y; ms.z += wm * v.z; ms.w += wm * v.w;
    ss.x += ww * v.x; ss.y += ww * v.y; ss.z += ww * v.z; ss.w += ww * v.w;
  }
  for (int i = stream + RTRIPS * 8; i < n; i += 8) {  // rare tail (n > 104)
    const int t = s_idx[i];
    const float wm = s_wm[i], ww = s_ww[i];
    const float4 v = *(const float4*)(rowbase + t * DD);
    ms.x += wm * v.x; ms.y += wm * v.y; ms.z += wm * v.z; ms.w += wm * v.w;
    ss.x += ww * v.x; ss.y += ww * v.y; ss.z += ww * v.z; ss.w += ww * v.w;
  }
  *(float4*)&s_pa[stream * DD + lane32 * 4] = ms;
  *(float4*)&s_pb[stream * DD + lane32 * 4] = ss;
  __syncthreads();

  float short_v = 0.f;
  if (tid < DD) {
    float am = 0.f, as = 0.f;
#pragma unroll
    for (int s = 0; s < 8; ++s) { am += s_pa[s * DD + tid]; as += s_pb[s * DD + tid]; }
    s_mean[tid] = am / (cntf + 1e-6f);
    short_v = as / dn;  // kept in register until the blend
  } else if (tid == DD) {
    float sp = 0.f, sr = 0.f;
    for (int t = lo; t < cnt; ++t) {
      sp += pop[(size_t)b * TT + t];
      sr += age[(size_t)b * TT + t];
    }
    const float z = gate_w[0] * (sp / dn) + gate_w[1] * (sr / dn) + gate_b[0];
    s_scal[1] = 1.f / (1.f + expf(-z));
  }
  __syncthreads();

  // ---- qk = A_scaled * mean (A is L2-resident across blocks) ----
  if (tid < DD) {
    const float4* Ar = (const float4*)(A + tid * DD);
    float acc = 0.f;
#pragma unroll
    for (int j = 0; j < DD / 4; ++j) {
      const float4 a4 = Ar[j];
      acc += a4.x * s_mean[4 * j] + a4.y * s_mean[4 * j + 1] +
             a4.z * s_mean[4 * j + 2] + a4.w * s_mean[4 * j + 3];
    }
    s_qk[tid] = acc;
  }
  __syncthreads();

  // ---- pass 2: replay from registers -> max-free softmax-weighted sum ----
  const float4 qk = *(const float4*)&s_qk[lane32 * 4];
  float l = 0.f;
  float4 o = {0.f, 0.f, 0.f, 0.f};
#pragma unroll
  for (int j = 0; j < RTRIPS; ++j) {
    const int i = stream + j * 8;
    if (i < n) {
      const float df = s_df[i];
      const float4 v = r[j];
      float p = qk.x * v.x + qk.y * v.y + qk.z * v.z + qk.w * v.w;
      p += __shfl_xor(p, 1);
      p += __shfl_xor(p, 2);
      p += __shfl_xor(p, 4);
      p += __shfl_xor(p, 8);
      p += __shfl_xor(p, 16);
      const float e = __expf(p) * df;  // df=0 kills window-only rows
      l += e;
      o.x += e * v.x; o.y += e * v.y; o.z += e * v.z; o.w += e * v.w;
    }
  }
  for (int i = stream + RTRIPS * 8; i < n; i += 8) {  // rare tail, L2/L3-warm
    const int t = s_idx[i];
    const float df = s_df[i];
    const float4 v = *(const float4*)(rowbase + t * DD);
    float p = qk.x * v.x + qk.y * v.y + qk.z * v.z + qk.w * v.w;
    p += __shfl_xor(p, 1);
    p += __shfl_xor(p, 2);
    p += __shfl_xor(p, 4);
    p += __shfl_xor(p, 8);
    p += __shfl_xor(p, 16);
    const float e = __expf(p) * df;
    l += e;
    o.x += e * v.x; o.y += e * v.y; o.z += e * v.z; o.w += e * v.w;
  }
  *(float4*)&s_pa[stream * DD + lane32 * 4] = o;
  if (lane32 == 0) s_l[stream] = l;
  __syncthreads();

  // ---- merge streams (plain sums — no max bookkeeping) ----
  if (tid < DD) {
    float O = 0.f;
#pragma unroll
    for (int s = 0; s < 8; ++s) O += s_pa[s * DD + tid];
    float L = 0.f;
#pragma unroll
    for (int s = 0; s < 8; ++s) L += s_l[s];
    s_w[tid] = O / L;
  }
  __syncthreads();

  // ---- long_term = Wv * weighted; gate blend ----
  if (tid < DD) {
    const float4* Wr = (const float4*)(Wv + tid * DD);
    float acc = 0.f;
#pragma unroll
    for (int j = 0; j < DD / 4; ++j) {
      const float4 a4 = Wr[j];
      acc += a4.x * s_w[4 * j] + a4.y * s_w[4 * j + 1] +
             a4.z * s_w[4 * j + 2] + a4.w * s_w[4 * j + 3];
    }
    const float g = s_scal[1];
    s_user[tid] = g * short_v + (1.f - g) * acc;
  }
  __syncthreads();

  // ---- LayerNorm ----
  if (tid < 64) {
    const float x0 = s_user[tid], x1 = s_user[64 + tid];
    float su = x0 + x1;
#pragma unroll
    for (int off2 = 32; off2 > 0; off2 >>= 1) su += __shfl_xor(su, off2);
    const float mu = su * (1.f / 128.f);
    const float d0 = x0 - mu, d1 = x1 - mu;
    float s2 = d0 * d0 + d1 * d1;
#pragma unroll
    for (int off2 = 32; off2 > 0; off2 >>= 1) s2 += __shfl_xor(s2, off2);
    if (tid == 0) {
      s_scal[4] = mu;
      s_scal[5] = 1.f / sqrtf(s2 * (1.f / 128.f) + 1e-5f);
    }
  }
  __syncthreads();

  if (tid < DD) {
    out[(size_t)b * DD + tid] =
        (s_user[tid] - s_scal[4]) * s_scal[5] * gamma[tid] + beta[tid];
  }
}

// ---------------------------------------------------------------------------
extern "C" void kernel_launch(void* const* d_in, const int* in_sizes, int n_in,
                              void* d_out, int out_size, void* d_ws, size_t ws_size,
                              hipStream_t stream) {
  const float* items  = (const float*)d_in[0];
  const void*  maskp  = d_in[1];
  const float* age    = (const float*)d_in[2];
  const float* pop    = (const float*)d_in[3];
  const float* Wq     = (const float*)d_in[4];
  const float* Wk     = (const float*)d_in[5];
  const float* Wv     = (const float*)d_in[6];
  const float* gate_w = (const float*)d_in[7];
  const float* gate_b = (const float*)d_in[8];
  const float* gamma  = (const float*)d_in[9];
  const float* beta   = (const float*)d_in[10];
  const float* alpha  = (const float*)d_in[11];

  char* ws = (char*)d_ws;
  int*   flag = (int*)ws;            // 256 B
  float* A    = (float*)(ws + 256);  // 64 KB
  float* outp = (float*)d_out;

  precompute_A_kernel<<<DD, DD, 0, stream>>>(Wq, Wk, A, (const unsigned*)maskp, flag);
  fused_kernel<<<BB, 256, 0, stream>>>(items, maskp, age, pop, Wv, gate_w,
                                       gate_b, gamma, beta, alpha, A, flag,
                                       outp);
}